// Round 2
// baseline (990.939 us; speedup 1.0000x reference)
//
#include <hip/hip_runtime.h>
#include <hip/hip_bf16.h>

// Problem constants (from reference)
#define NN 16384   // N_NODES
#define KK 50      // K neighbors
#define DD 64      // EMBED_DIM

// ---------- bf16 helpers (raw u16 view; RTNE on store) ----------
__device__ __forceinline__ float bf2f(unsigned short u) {
    union { unsigned int i; float f; } v;
    v.i = ((unsigned int)u) << 16;
    return v.f;
}
__device__ __forceinline__ unsigned short f2bf(float f) {
    union { float f; unsigned int i; } v; v.f = f;
    unsigned int lsb = (v.i >> 16) & 1u;
    v.i += 0x7fffu + lsb;                 // round-to-nearest-even
    return (unsigned short)(v.i >> 16);
}

// dtype-dispatched scalar load
template<int BF16>
__device__ __forceinline__ float ldv(const void* p, size_t i) {
    if (BF16) return bf2f(((const unsigned short*)p)[i]);
    else      return ((const float*)p)[i];
}

// ---------- dtype probes (one wave) ----------
// flags[0]: neigh_mask is uint8 (1) vs int32 (0)
//   int32 {0,1} -> every 32-bit word <= 1; u8 ~50% ones -> some word > 1.
// flags[1]: table is bf16-packed (1) vs float32 (0)
//   bf16 pair in a word: LOW u16 is a bf16 of N(0,0.02): exponent in [96,126] ~always.
//   f32: low u16 = uniform mantissa bits: in-range ~12%. popcount over 64 words.
__global__ void probe_kernel(const unsigned int* __restrict__ tw,
                             const unsigned int* __restrict__ mw,
                             int* __restrict__ flags) {
    const int t = threadIdx.x;   // 64 lanes
    // --- table dtype ---
    const unsigned int w  = tw[t];
    const unsigned int lo = w & 0xFFFFu;
    const unsigned int ex = (lo >> 7) & 0xFFu;
    const bool bf_like = (ex >= 96u && ex <= 126u);
    const unsigned long long bb = __ballot(bf_like);
    // --- mask dtype ---
    bool found = false;
#pragma unroll
    for (int i = 0; i < 8; ++i) found |= (mw[t + i * 64] > 1u);
    const unsigned long long mb = __ballot(found);
    if (t == 0) {
        flags[0] = (mb != 0ull) ? 1 : 0;
        flags[1] = (__popcll(bb) >= 48) ? 1 : 0;
    }
}

// ---------- main kernel: one wave (64 lanes) per node ----------
template<int BF16>
__global__ __launch_bounds__(64) void agg_kernel(
    const void* __restrict__ table_,    // [1M x 64]
    const void* __restrict__ W1_,       // [128 x 64]
    const void* __restrict__ b1_,       // [64]
    const void* __restrict__ W2_,       // [64 x 64]
    const void* __restrict__ b2_,       // [64]
    const void* __restrict__ W3_,       // [64]
    const void* __restrict__ b3_,       // [1]
    const int*  __restrict__ nodes,     // [N]
    const int*  __restrict__ neigh_idx, // [N x K]
    const void* __restrict__ neigh_mask,// [N x K] uint8 OR int32
    const int*  __restrict__ flags,
    void*       __restrict__ out_)      // [N x 64], dtype matches inputs
{
    if (flags[1] != BF16) return;       // wrong-dtype instantiation: no-op
    const int mu8 = flags[0];

    __shared__ float x_sh[128];   // [E(64) | U(64)]
    __shared__ float h_sh[64];

    const int n = blockIdx.x;
    const int j = threadIdx.x;

    // center embedding -> x[64..127]
    const size_t node = (size_t)nodes[n];
    x_sh[64 + j] = ldv<BF16>(table_, node * 64 + j);

    const float b1j = ldv<BF16>(b1_, j);
    const float b2j = ldv<BF16>(b2_, j);
    const float w3j = ldv<BF16>(W3_, j);
    const float b3v = ldv<BF16>(b3_, 0);

    // online softmax state
    float m   = -3.0e38f;
    float l   = 0.0f;
    float acc = 0.0f;

    for (int k = 0; k < KK; ++k) {
        bool mk;
        if (mu8) mk = ((const unsigned char*)neigh_mask)[(size_t)n * KK + k] != 0;
        else     mk = ((const int*)neigh_mask)[(size_t)n * KK + k] != 0;
        if (!mk) continue;   // uniform across the single wave of this block

        const size_t idx = (size_t)neigh_idx[(size_t)n * KK + k];
        const float  e   = ldv<BF16>(table_, idx * 64 + j);

        __syncthreads();            // previous iter's x_sh reads done
        x_sh[j] = e;
        __syncthreads();

        // h1[j] = relu(b1[j] + sum_i x[i] * W1[i][j]),  i in [0,128)
        float h1 = b1j;
        const float4* x4 = (const float4*)x_sh;
#pragma unroll 8
        for (int i4 = 0; i4 < 32; ++i4) {
            const float4 xv = x4[i4];
            const int i = i4 * 4;
            h1 += xv.x * ldv<BF16>(W1_, (size_t)(i + 0) * 64 + j);
            h1 += xv.y * ldv<BF16>(W1_, (size_t)(i + 1) * 64 + j);
            h1 += xv.z * ldv<BF16>(W1_, (size_t)(i + 2) * 64 + j);
            h1 += xv.w * ldv<BF16>(W1_, (size_t)(i + 3) * 64 + j);
        }
        h1 = fmaxf(h1, 0.0f);

        __syncthreads();
        h_sh[j] = h1;
        __syncthreads();

        // h2[j] = relu(b2[j] + sum_i h1[i] * W2[i][j]),  i in [0,64)
        float h2 = b2j;
        const float4* h4 = (const float4*)h_sh;
#pragma unroll 8
        for (int i4 = 0; i4 < 16; ++i4) {
            const float4 hv = h4[i4];
            const int i = i4 * 4;
            h2 += hv.x * ldv<BF16>(W2_, (size_t)(i + 0) * 64 + j);
            h2 += hv.y * ldv<BF16>(W2_, (size_t)(i + 1) * 64 + j);
            h2 += hv.z * ldv<BF16>(W2_, (size_t)(i + 2) * 64 + j);
            h2 += hv.w * ldv<BF16>(W2_, (size_t)(i + 3) * 64 + j);
        }
        h2 = fmaxf(h2, 0.0f);

        // s = b3 + sum_j h2[j] * W3[j]  (64-lane butterfly reduction)
        float p = h2 * w3j;
#pragma unroll
        for (int off = 32; off > 0; off >>= 1)
            p += __shfl_xor(p, off, 64);
        const float s = p + b3v;

        // online softmax update
        const float mn    = fmaxf(m, s);
        const float scale = expf(m - mn);
        const float w     = expf(s - mn);
        l   = l * scale + w;
        acc = acc * scale + w * e;
        m   = mn;
    }

    const float res = acc / l;   // l >= 1: mask[:,0] always true
    if (BF16) ((unsigned short*)out_)[(size_t)n * 64 + j] = f2bf(res);
    else      ((float*)out_)[(size_t)n * 64 + j] = res;
}

extern "C" void kernel_launch(void* const* d_in, const int* in_sizes, int n_in,
                              void* d_out, int out_size, void* d_ws, size_t ws_size,
                              hipStream_t stream) {
    const void* table = d_in[0];
    const void* W1    = d_in[1];
    const void* b1    = d_in[2];
    const void* W2    = d_in[3];
    const void* b2    = d_in[4];
    const void* W3    = d_in[5];
    const void* b3    = d_in[6];
    const int*  nodes = (const int*)d_in[7];
    const int*  nidx  = (const int*)d_in[8];
    const void* nmask = d_in[9];

    int* flags = (int*)d_ws;

    probe_kernel<<<1, 64, 0, stream>>>((const unsigned int*)table,
                                       (const unsigned int*)nmask, flags);
    agg_kernel<0><<<NN, 64, 0, stream>>>(table, W1, b1, W2, b2, W3, b3,
                                         nodes, nidx, nmask, flags, d_out);
    agg_kernel<1><<<NN, 64, 0, stream>>>(table, W1, b1, W2, b2, W3, b3,
                                         nodes, nidx, nmask, flags, d_out);
}

// Round 3
// 520.508 us; speedup vs baseline: 1.9038x; 1.9038x over previous
//
#include <hip/hip_runtime.h>
#include <hip/hip_bf16.h>

#define NN 16384   // N_NODES
#define KK 50      // K neighbors
#define DD 64      // EMBED_DIM

typedef __attribute__((ext_vector_type(8))) short bf16x8;   // 8 bf16 (4 VGPRs)
typedef __attribute__((ext_vector_type(4))) float f32x4;    // MFMA C/D

// ---------- bf16 helpers ----------
__device__ __forceinline__ float bf2f(unsigned short u) {
    union { unsigned int i; float f; } v;
    v.i = ((unsigned int)u) << 16;
    return v.f;
}
__device__ __forceinline__ unsigned short f2bf(float f) {
    union { float f; unsigned int i; } v; v.f = f;
    unsigned int lsb = (v.i >> 16) & 1u;
    v.i += 0x7fffu + lsb;                 // RTNE
    return (unsigned short)(v.i >> 16);
}

template<int BF16>
__device__ __forceinline__ float ldv(const void* p, size_t i) {
    if (BF16) return bf2f(((const unsigned short*)p)[i]);
    else      return ((const float*)p)[i];
}

// 8 consecutive elements starting at off (off % 8 == 0) -> bf16x8
template<int BF16>
__device__ __forceinline__ bf16x8 load8(const void* p, size_t off) {
    if (BF16) {
        return *(const bf16x8*)((const unsigned short*)p + off);   // 16B
    } else {
        const float* f = (const float*)p + off;
        bf16x8 r;
#pragma unroll
        for (int j = 0; j < 8; ++j) ((unsigned short*)&r)[j] = f2bf(f[j]);
        return r;
    }
}

// ---------- dtype probes (one wave) ----------
__global__ void probe_kernel(const unsigned int* __restrict__ tw,
                             const unsigned int* __restrict__ mw,
                             int* __restrict__ flags) {
    const int t = threadIdx.x;   // 64 lanes
    const unsigned int w  = tw[t];
    const unsigned int lo = w & 0xFFFFu;
    const unsigned int ex = (lo >> 7) & 0xFFu;
    const bool bf_like = (ex >= 96u && ex <= 126u);
    const unsigned long long bb = __ballot(bf_like);
    bool found = false;
#pragma unroll
    for (int i = 0; i < 8; ++i) found |= (mw[t + i * 64] > 1u);
    const unsigned long long mb = __ballot(found);
    if (t == 0) {
        flags[0] = (mb != 0ull) ? 1 : 0;   // mask is uint8
        flags[1] = (__popcll(bb) >= 48) ? 1 : 0;   // table is bf16
    }
}

// ---------- weight repack: W1 [128x64], W2 [64x64] -> MFMA B-fragment order ----------
// B fragment (16x16x32): lane holds B[k = kt*32 + (lane>>4)*8 + j][n = nt*16 + (lane&15)]
// packed as [frag=kt*4+nt][lane][j] contiguous bf16.
__global__ void prep_kernel(const void* __restrict__ W1_,
                            const void* __restrict__ W2_,
                            const int*  __restrict__ flags,
                            unsigned short* __restrict__ W1p,
                            unsigned short* __restrict__ W2p) {
    const int t  = threadIdx.x;            // 1024 threads
    const int bf = flags[1];
    {   // W1: 16 fragments
        const int f = t >> 6, lane = t & 63;
        const int kt = f >> 2, nt = f & 3;
        const int q = lane >> 4, col = lane & 15;
#pragma unroll
        for (int j = 0; j < 8; ++j) {
            const int k = kt * 32 + q * 8 + j;
            const int n = nt * 16 + col;
            const float v = bf ? bf2f(((const unsigned short*)W1_)[k * 64 + n])
                               : ((const float*)W1_)[k * 64 + n];
            W1p[((size_t)f * 64 + lane) * 8 + j] = f2bf(v);
        }
    }
    if (t < 512) {   // W2: 8 fragments
        const int f = t >> 6, lane = t & 63;
        const int kt = f >> 2, nt = f & 3;
        const int q = lane >> 4, col = lane & 15;
#pragma unroll
        for (int j = 0; j < 8; ++j) {
            const int k = kt * 32 + q * 8 + j;
            const int n = nt * 16 + col;
            const float v = bf ? bf2f(((const unsigned short*)W2_)[k * 64 + n])
                               : ((const float*)W2_)[k * 64 + n];
            W2p[((size_t)f * 64 + lane) * 8 + j] = f2bf(v);
        }
    }
}

// ---------- main: one wave per node, 4 waves/block ----------
template<int BF16>
__global__ __launch_bounds__(256) void agg_mfma_kernel(
    const void* __restrict__ table_,     // [1M x 64]
    const void* __restrict__ b1_,        // [64]
    const void* __restrict__ b2_,        // [64]
    const void* __restrict__ W3_,        // [64]
    const void* __restrict__ b3_,        // [1]
    const int*  __restrict__ nodes,      // [N]
    const int*  __restrict__ neigh_idx,  // [N x K]
    const void* __restrict__ neigh_mask, // [N x K] uint8 OR int32
    const int*  __restrict__ flags,
    const unsigned short* __restrict__ W1p,
    const unsigned short* __restrict__ W2p,
    void*       __restrict__ out_)
{
    if (flags[1] != BF16) return;        // wrong-dtype instantiation: no-op
    const int mu8 = flags[0];

    const int wave = threadIdx.x >> 6;
    const int lane = threadIdx.x & 63;
    const int n    = blockIdx.x * 4 + wave;   // node
    const int q    = lane >> 4;
    const int col  = lane & 15;

    // per-wave LDS: H1 [64 x 64] bf16, rows padded to 72 elems (144 B, keeps
    // 16B alignment for ds_read_b128), + att broadcast buffer
    __shared__ unsigned short h1_sh[4][64][72];
    __shared__ float att_sh[4][64];

    // --- row indices for A fragments: row m = mt*16 + col ---
    int  rowidx [4];
    bool rowmask[4];
#pragma unroll
    for (int mt = 0; mt < 4; ++mt) {
        const int k = mt * 16 + col;     // neighbor slot
        bool mk = false; int idx = 0;
        if (k < KK) {
            mk = mu8 ? (((const unsigned char*)neigh_mask)[(size_t)n * KK + k] != 0)
                     : (((const int*)neigh_mask)[(size_t)n * KK + k] != 0);
            if (mk) idx = neigh_idx[(size_t)n * KK + k];   // masked rows read row 0
        }
        rowidx[mt] = idx; rowmask[mt] = mk;
    }

    // --- A fragments: E half (kt=0,1 -> k 0..63) gathered per row ---
    bf16x8 afrag[4][2];
#pragma unroll
    for (int mt = 0; mt < 4; ++mt)
#pragma unroll
        for (int kt = 0; kt < 2; ++kt)
            afrag[mt][kt] = load8<BF16>(table_, (size_t)rowidx[mt] * 64 + kt * 32 + q * 8);

    // --- center half (kt=2,3 -> U broadcast, same for all rows) ---
    const size_t node = (size_t)nodes[n];
    bf16x8 ufrag[2];
#pragma unroll
    for (int kt = 0; kt < 2; ++kt)
        ufrag[kt] = load8<BF16>(table_, node * 64 + kt * 32 + q * 8);

    // --- layer 1: acc1[mt][nt] = X @ W1  (64 MFMAs) ---
    f32x4 acc1[4][4];
#pragma unroll
    for (int mt = 0; mt < 4; ++mt)
#pragma unroll
        for (int nt = 0; nt < 4; ++nt) acc1[mt][nt] = (f32x4){0.f, 0.f, 0.f, 0.f};

#pragma unroll
    for (int kt = 0; kt < 4; ++kt) {
#pragma unroll
        for (int nt = 0; nt < 4; ++nt) {
            const bf16x8 b = *(const bf16x8*)(W1p + ((size_t)(kt * 4 + nt) * 64 + lane) * 8);
#pragma unroll
            for (int mt = 0; mt < 4; ++mt) {
                const bf16x8 a = (kt < 2) ? afrag[mt][kt] : ufrag[kt - 2];
                acc1[mt][nt] = __builtin_amdgcn_mfma_f32_16x16x32_bf16(a, b, acc1[mt][nt], 0, 0, 0);
            }
        }
    }

    // --- bias + relu, C layout -> LDS (A-layout-readable) ---
    float b1v[4];
#pragma unroll
    for (int nt = 0; nt < 4; ++nt) b1v[nt] = ldv<BF16>(b1_, nt * 16 + col);
#pragma unroll
    for (int mt = 0; mt < 4; ++mt)
#pragma unroll
        for (int nt = 0; nt < 4; ++nt)
#pragma unroll
            for (int r = 0; r < 4; ++r) {
                const float v = fmaxf(acc1[mt][nt][r] + b1v[nt], 0.f);
                h1_sh[wave][mt * 16 + q * 4 + r][nt * 16 + col] = f2bf(v);
            }

    // --- layer 2: acc2 = H1 @ W2  (32 MFMAs) ---
    f32x4 acc2[4][4];
#pragma unroll
    for (int mt = 0; mt < 4; ++mt)
#pragma unroll
        for (int nt = 0; nt < 4; ++nt) acc2[mt][nt] = (f32x4){0.f, 0.f, 0.f, 0.f};

#pragma unroll
    for (int kt = 0; kt < 2; ++kt) {
        bf16x8 a2[4];
#pragma unroll
        for (int mt = 0; mt < 4; ++mt)
            a2[mt] = *(const bf16x8*)&h1_sh[wave][mt * 16 + col][kt * 32 + q * 8];
#pragma unroll
        for (int nt = 0; nt < 4; ++nt) {
            const bf16x8 b = *(const bf16x8*)(W2p + ((size_t)(kt * 4 + nt) * 64 + lane) * 8);
#pragma unroll
            for (int mt = 0; mt < 4; ++mt)
                acc2[mt][nt] = __builtin_amdgcn_mfma_f32_16x16x32_bf16(a2[mt], b, acc2[mt][nt], 0, 0, 0);
        }
    }

    // --- scores: s[row] = b3 + sum_n relu(acc2 + b2)[row][n] * W3[n] ---
    float b2v[4], w3v[4];
#pragma unroll
    for (int nt = 0; nt < 4; ++nt) {
        b2v[nt] = ldv<BF16>(b2_, nt * 16 + col);
        w3v[nt] = ldv<BF16>(W3_, nt * 16 + col);
    }
    const float b3v = ldv<BF16>(b3_, 0);

    float s[4][4];   // [mt][r]: row = mt*16 + q*4 + r
#pragma unroll
    for (int mt = 0; mt < 4; ++mt) {
        const unsigned long long bm = __ballot(rowmask[mt]);   // bit l = mask of row mt*16+(l&15)
#pragma unroll
        for (int r = 0; r < 4; ++r) {
            float p = 0.f;
#pragma unroll
            for (int nt = 0; nt < 4; ++nt)
                p += fmaxf(acc2[mt][nt][r] + b2v[nt], 0.f) * w3v[nt];
            p += __shfl_xor(p, 1, 64);
            p += __shfl_xor(p, 2, 64);
            p += __shfl_xor(p, 4, 64);
            p += __shfl_xor(p, 8, 64);
            const bool mk = (bm >> (q * 4 + r)) & 1ull;
            s[mt][r] = mk ? (p + b3v) : -1.0e30f;
        }
    }

    // --- masked softmax over 64 rows (each lane holds 16; quads partition rows) ---
    float mx = -3.0e38f;
#pragma unroll
    for (int mt = 0; mt < 4; ++mt)
#pragma unroll
        for (int r = 0; r < 4; ++r) mx = fmaxf(mx, s[mt][r]);
    mx = fmaxf(mx, __shfl_xor(mx, 16, 64));
    mx = fmaxf(mx, __shfl_xor(mx, 32, 64));

    float e[4][4], lsum = 0.f;
#pragma unroll
    for (int mt = 0; mt < 4; ++mt)
#pragma unroll
        for (int r = 0; r < 4; ++r) {
            e[mt][r] = expf(s[mt][r] - mx);
            lsum += e[mt][r];
        }
    lsum += __shfl_xor(lsum, 16, 64);
    lsum += __shfl_xor(lsum, 32, 64);
    const float inv = 1.f / lsum;

    if (col == 0)
#pragma unroll
        for (int mt = 0; mt < 4; ++mt)
#pragma unroll
            for (int r = 0; r < 4; ++r)
                att_sh[wave][mt * 16 + q * 4 + r] = e[mt][r] * inv;

    // --- out[d] = sum_k att[k] * E[k][d]  (d = lane; rows L2-hot) ---
    float acc = 0.f;
    for (int k = 0; k < KK; ++k) {
        const float a = att_sh[wave][k];   // wave-uniform
        if (a != 0.f) {
            const size_t idx = (size_t)neigh_idx[(size_t)n * KK + k];
            acc += a * ldv<BF16>(table_, idx * 64 + lane);
        }
    }

    if (BF16) ((unsigned short*)out_)[(size_t)n * 64 + lane] = f2bf(acc);
    else      ((float*)out_)[(size_t)n * 64 + lane] = acc;
}

extern "C" void kernel_launch(void* const* d_in, const int* in_sizes, int n_in,
                              void* d_out, int out_size, void* d_ws, size_t ws_size,
                              hipStream_t stream) {
    const void* table = d_in[0];
    const void* W1    = d_in[1];
    const void* b1    = d_in[2];
    const void* W2    = d_in[3];
    const void* b2    = d_in[4];
    const void* W3    = d_in[5];
    const void* b3    = d_in[6];
    const int*  nodes = (const int*)d_in[7];
    const int*  nidx  = (const int*)d_in[8];
    const void* nmask = d_in[9];

    int* flags = (int*)d_ws;
    unsigned short* W1p = (unsigned short*)((char*)d_ws + 1024);           // 16 KB
    unsigned short* W2p = (unsigned short*)((char*)d_ws + 1024 + 16384);   // 8 KB

    probe_kernel<<<1, 64, 0, stream>>>((const unsigned int*)table,
                                       (const unsigned int*)nmask, flags);
    prep_kernel<<<1, 1024, 0, stream>>>(W1, W2, flags, W1p, W2p);

    agg_mfma_kernel<0><<<NN / 4, 256, 0, stream>>>(table, b1, b2, W3, b3,
                                                   nodes, nidx, nmask, flags,
                                                   W1p, W2p, d_out);
    agg_mfma_kernel<1><<<NN / 4, 256, 0, stream>>>(table, b1, b2, W3, b3,
                                                   nodes, nidx, nmask, flags,
                                                   W1p, W2p, d_out);
}

// Round 4
// 413.970 us; speedup vs baseline: 2.3937x; 1.2574x over previous
//
#include <hip/hip_runtime.h>
#include <hip/hip_bf16.h>

#define NN 16384   // N_NODES
#define KK 50      // K neighbors
#define DD 64      // EMBED_DIM

typedef __attribute__((ext_vector_type(8))) short bf16x8;   // 8 bf16 (4 VGPRs)
typedef __attribute__((ext_vector_type(4))) float f32x4;    // MFMA C/D

// ---------- bf16 helpers ----------
__device__ __forceinline__ float bf2f(unsigned short u) {
    union { unsigned int i; float f; } v;
    v.i = ((unsigned int)u) << 16;
    return v.f;
}
__device__ __forceinline__ unsigned short f2bf(float f) {
    union { float f; unsigned int i; } v; v.f = f;
    unsigned int lsb = (v.i >> 16) & 1u;
    v.i += 0x7fffu + lsb;                 // RTNE
    return (unsigned short)(v.i >> 16);
}

template<int BF16>
__device__ __forceinline__ float ldv(const void* p, size_t i) {
    if (BF16) return bf2f(((const unsigned short*)p)[i]);
    else      return ((const float*)p)[i];
}

// 8 consecutive elements starting at off (off % 8 == 0) -> bf16x8
template<int BF16>
__device__ __forceinline__ bf16x8 load8(const void* p, size_t off) {
    if (BF16) {
        return *(const bf16x8*)((const unsigned short*)p + off);   // 16B
    } else {
        const float* f = (const float*)p + off;
        bf16x8 r;
#pragma unroll
        for (int j = 0; j < 8; ++j) ((unsigned short*)&r)[j] = f2bf(f[j]);
        return r;
    }
}

// ---------- combined probe + weight repack (one block, 1024 threads) ----------
// flags[0]: neigh_mask is uint8 (1) vs int32 (0)
// flags[1]: table is bf16-packed (1) vs float32 (0)
// B fragment (16x16x32): lane holds B[k = kt*32 + (lane>>4)*8 + j][n = nt*16 + (lane&15)]
// packed as [frag=kt*4+nt][lane][j] contiguous bf16.
__global__ void prep_kernel(const unsigned int* __restrict__ tw,
                            const unsigned int* __restrict__ mw,
                            const void* __restrict__ W1_,
                            const void* __restrict__ W2_,
                            int* __restrict__ flags,
                            unsigned short* __restrict__ W1p,
                            unsigned short* __restrict__ W2p) {
    __shared__ int sflags[2];
    const int t = threadIdx.x;            // 1024
    if (t < 64) {
        const unsigned int w  = tw[t];
        const unsigned int lo = w & 0xFFFFu;
        const unsigned int ex = (lo >> 7) & 0xFFu;
        const bool bf_like = (ex >= 96u && ex <= 126u);
        const unsigned long long bb = __ballot(bf_like);
        bool found = false;
#pragma unroll
        for (int i = 0; i < 8; ++i) found |= (mw[t + i * 64] > 1u);
        const unsigned long long mb = __ballot(found);
        if (t == 0) {
            sflags[0] = (mb != 0ull) ? 1 : 0;
            sflags[1] = (__popcll(bb) >= 48) ? 1 : 0;
            flags[0] = sflags[0];
            flags[1] = sflags[1];
        }
    }
    __syncthreads();
    const int bf = sflags[1];
    {   // W1 [128x64]: 16 fragments
        const int f = t >> 6, lane = t & 63;
        const int kt = f >> 2, nt = f & 3;
        const int q = lane >> 4, col = lane & 15;
#pragma unroll
        for (int j = 0; j < 8; ++j) {
            const int k = kt * 32 + q * 8 + j;
            const int n = nt * 16 + col;
            const float v = bf ? bf2f(((const unsigned short*)W1_)[k * 64 + n])
                               : ((const float*)W1_)[k * 64 + n];
            W1p[((size_t)f * 64 + lane) * 8 + j] = f2bf(v);
        }
    }
    if (t < 512) {   // W2 [64x64]: 8 fragments
        const int f = t >> 6, lane = t & 63;
        const int kt = f >> 2, nt = f & 3;
        const int q = lane >> 4, col = lane & 15;
#pragma unroll
        for (int j = 0; j < 8; ++j) {
            const int k = kt * 32 + q * 8 + j;
            const int n = nt * 16 + col;
            const float v = bf ? bf2f(((const unsigned short*)W2_)[k * 64 + n])
                               : ((const float*)W2_)[k * 64 + n];
            W2p[((size_t)f * 64 + lane) * 8 + j] = f2bf(v);
        }
    }
}

// ---------- main computation: one wave per node ----------
template<int BF16>
__device__ __forceinline__ void agg_impl(
    const void* __restrict__ table_,
    const void* __restrict__ b1_, const void* __restrict__ b2_,
    const void* __restrict__ W3_, const void* __restrict__ b3_,
    const int*  __restrict__ nodes,
    const int*  __restrict__ neigh_idx,
    const void* __restrict__ neigh_mask,
    int mu8,
    const unsigned short* __restrict__ W1p,
    const unsigned short* __restrict__ W2p,
    unsigned short* __restrict__ h1,     // per-wave [64][72] bf16 (rows 144B, 16B-aligned)
    float* __restrict__ scr,             // per-wave [64] f32 scratch (att, then out)
    void* __restrict__ out_)
{
    const int wave = threadIdx.x >> 6;
    const int lane = threadIdx.x & 63;
    const int n    = blockIdx.x * 4 + wave;
    const int q    = lane >> 4;
    const int col  = lane & 15;

    // --- row indices + mask: A-layout row m = mt*16 + col ---
    int  rowidx [4];
    bool rowmask[4];
#pragma unroll
    for (int mt = 0; mt < 4; ++mt) {
        const int k = mt * 16 + col;
        bool mk = false; int idx = 0;
        if (k < KK) {
            mk = mu8 ? (((const unsigned char*)neigh_mask)[(size_t)n * KK + k] != 0)
                     : (((const int*)neigh_mask)[(size_t)n * KK + k] != 0);
            if (mk) idx = neigh_idx[(size_t)n * KK + k];   // masked rows read row 0
        }
        rowidx[mt] = idx; rowmask[mt] = mk;
    }

    // --- gather E rows (A fragments, kept live for the final weighted sum) ---
    bf16x8 afrag[4][2];
#pragma unroll
    for (int mt = 0; mt < 4; ++mt)
#pragma unroll
        for (int kt = 0; kt < 2; ++kt)
            afrag[mt][kt] = load8<BF16>(table_, (size_t)rowidx[mt] * 64 + kt * 32 + q * 8);

    const size_t node = (size_t)nodes[n];
    bf16x8 ufrag[2];
#pragma unroll
    for (int kt = 0; kt < 2; ++kt)
        ufrag[kt] = load8<BF16>(table_, node * 64 + kt * 32 + q * 8);

    // --- layer 1: acc1 = [E | U] @ W1  (64 MFMAs) ---
    f32x4 acc1[4][4];
#pragma unroll
    for (int mt = 0; mt < 4; ++mt)
#pragma unroll
        for (int nt = 0; nt < 4; ++nt) acc1[mt][nt] = (f32x4){0.f, 0.f, 0.f, 0.f};

#pragma unroll
    for (int kt = 0; kt < 4; ++kt) {
#pragma unroll
        for (int nt = 0; nt < 4; ++nt) {
            const bf16x8 b = *(const bf16x8*)(W1p + ((size_t)(kt * 4 + nt) * 64 + lane) * 8);
#pragma unroll
            for (int mt = 0; mt < 4; ++mt) {
                const bf16x8 a = (kt < 2) ? afrag[mt][kt] : ufrag[kt - 2];
                acc1[mt][nt] = __builtin_amdgcn_mfma_f32_16x16x32_bf16(a, b, acc1[mt][nt], 0, 0, 0);
            }
        }
    }

    // --- bias + relu, C layout -> LDS (A-layout-readable) ---
    float b1v[4];
#pragma unroll
    for (int nt = 0; nt < 4; ++nt) b1v[nt] = ldv<BF16>(b1_, nt * 16 + col);
#pragma unroll
    for (int mt = 0; mt < 4; ++mt)
#pragma unroll
        for (int nt = 0; nt < 4; ++nt)
#pragma unroll
            for (int r = 0; r < 4; ++r) {
                const float v = fmaxf(acc1[mt][nt][r] + b1v[nt], 0.f);
                h1[(mt * 16 + q * 4 + r) * 72 + nt * 16 + col] = f2bf(v);
            }
    __builtin_amdgcn_wave_barrier();

    // --- layer 2: acc2 = H1 @ W2  (32 MFMAs) ---
    f32x4 acc2[4][4];
#pragma unroll
    for (int mt = 0; mt < 4; ++mt)
#pragma unroll
        for (int nt = 0; nt < 4; ++nt) acc2[mt][nt] = (f32x4){0.f, 0.f, 0.f, 0.f};

#pragma unroll
    for (int kt = 0; kt < 2; ++kt) {
        bf16x8 a2[4];
#pragma unroll
        for (int mt = 0; mt < 4; ++mt)
            a2[mt] = *(const bf16x8*)&h1[(mt * 16 + col) * 72 + kt * 32 + q * 8];
#pragma unroll
        for (int nt = 0; nt < 4; ++nt) {
            const bf16x8 b = *(const bf16x8*)(W2p + ((size_t)(kt * 4 + nt) * 64 + lane) * 8);
#pragma unroll
            for (int mt = 0; mt < 4; ++mt)
                acc2[mt][nt] = __builtin_amdgcn_mfma_f32_16x16x32_bf16(a2[mt], b, acc2[mt][nt], 0, 0, 0);
        }
    }

    // --- scores: s[row] = b3 + sum_n relu(acc2 + b2)[row][n] * W3[n] ---
    float b2v[4], w3v[4];
#pragma unroll
    for (int nt = 0; nt < 4; ++nt) {
        b2v[nt] = ldv<BF16>(b2_, nt * 16 + col);
        w3v[nt] = ldv<BF16>(W3_, nt * 16 + col);
    }
    const float b3v = ldv<BF16>(b3_, 0);

    float s[4][4];   // [mt][r]: row = mt*16 + q*4 + r
#pragma unroll
    for (int mt = 0; mt < 4; ++mt) {
        const unsigned long long bm = __ballot(rowmask[mt]);
#pragma unroll
        for (int r = 0; r < 4; ++r) {
            float p = 0.f;
#pragma unroll
            for (int nt = 0; nt < 4; ++nt)
                p += fmaxf(acc2[mt][nt][r] + b2v[nt], 0.f) * w3v[nt];
            p += __shfl_xor(p, 1, 64);
            p += __shfl_xor(p, 2, 64);
            p += __shfl_xor(p, 4, 64);
            p += __shfl_xor(p, 8, 64);
            const bool mk = (bm >> (q * 4 + r)) & 1ull;
            s[mt][r] = mk ? (p + b3v) : -1.0e30f;
        }
    }

    // --- masked softmax over 64 rows ---
    float mx = -3.0e38f;
#pragma unroll
    for (int mt = 0; mt < 4; ++mt)
#pragma unroll
        for (int r = 0; r < 4; ++r) mx = fmaxf(mx, s[mt][r]);
    mx = fmaxf(mx, __shfl_xor(mx, 16, 64));
    mx = fmaxf(mx, __shfl_xor(mx, 32, 64));

    float e[4][4], lsum = 0.f;
#pragma unroll
    for (int mt = 0; mt < 4; ++mt)
#pragma unroll
        for (int r = 0; r < 4; ++r) {
            e[mt][r] = expf(s[mt][r] - mx);   // masked rows: exp(-1e30-mx) == 0
            lsum += e[mt][r];
        }
    lsum += __shfl_xor(lsum, 16, 64);
    lsum += __shfl_xor(lsum, 32, 64);
    const float inv = 1.f / lsum;

    // --- broadcast att[row] to the row-owner lanes via 256B LDS scratch ---
    if (col == 0)
#pragma unroll
        for (int mt = 0; mt < 4; ++mt)
#pragma unroll
            for (int r = 0; r < 4; ++r)
                scr[mt * 16 + q * 4 + r] = e[mt][r] * inv;
    __builtin_amdgcn_wave_barrier();

    float attr[4];
#pragma unroll
    for (int mt = 0; mt < 4; ++mt) attr[mt] = scr[mt * 16 + col];   // broadcast reads

    // --- out[d] = sum_k att[k] * E[k][d], entirely from the live A-fragments ---
    // lane holds E[mt*16+col][kt*32+q*8+j]; weight by attr[mt], reduce across col lanes.
    float v[2][8];
#pragma unroll
    for (int kt = 0; kt < 2; ++kt)
#pragma unroll
        for (int j = 0; j < 8; ++j) v[kt][j] = 0.f;
#pragma unroll
    for (int mt = 0; mt < 4; ++mt)
#pragma unroll
        for (int kt = 0; kt < 2; ++kt)
#pragma unroll
            for (int j = 0; j < 8; ++j)
                v[kt][j] += attr[mt] * bf2f(((const unsigned short*)&afrag[mt][kt])[j]);

#pragma unroll
    for (int off = 1; off <= 8; off <<= 1)
#pragma unroll
        for (int kt = 0; kt < 2; ++kt)
#pragma unroll
            for (int j = 0; j < 8; ++j)
                v[kt][j] += __shfl_xor(v[kt][j], off, 64);

    __builtin_amdgcn_wave_barrier();
    if (col == 0)   // lanes 0,16,32,48 hold the full sums for their q-group's d's
#pragma unroll
        for (int kt = 0; kt < 2; ++kt)
#pragma unroll
            for (int j = 0; j < 8; ++j)
                scr[kt * 32 + q * 8 + j] = v[kt][j];
    __builtin_amdgcn_wave_barrier();

    const float res = scr[lane];
    if (BF16) ((unsigned short*)out_)[(size_t)n * 64 + lane] = f2bf(res);
    else      ((float*)out_)[(size_t)n * 64 + lane] = res;
}

__global__ __launch_bounds__(256) void agg_kernel(
    const void* __restrict__ table_,
    const void* __restrict__ b1_, const void* __restrict__ b2_,
    const void* __restrict__ W3_, const void* __restrict__ b3_,
    const int*  __restrict__ nodes,
    const int*  __restrict__ neigh_idx,
    const void* __restrict__ neigh_mask,
    const int*  __restrict__ flags,
    const unsigned short* __restrict__ W1p,
    const unsigned short* __restrict__ W2p,
    void* __restrict__ out_)
{
    __shared__ unsigned short h1_sh[4][64][72];
    __shared__ float scr_sh[4][64];
    const int wave = threadIdx.x >> 6;
    const int bf16 = flags[1];
    const int mu8  = flags[0];
    if (bf16)
        agg_impl<1>(table_, b1_, b2_, W3_, b3_, nodes, neigh_idx, neigh_mask, mu8,
                    W1p, W2p, &h1_sh[wave][0][0], &scr_sh[wave][0], out_);
    else
        agg_impl<0>(table_, b1_, b2_, W3_, b3_, nodes, neigh_idx, neigh_mask, mu8,
                    W1p, W2p, &h1_sh[wave][0][0], &scr_sh[wave][0], out_);
}

extern "C" void kernel_launch(void* const* d_in, const int* in_sizes, int n_in,
                              void* d_out, int out_size, void* d_ws, size_t ws_size,
                              hipStream_t stream) {
    const void* table = d_in[0];
    const void* W1    = d_in[1];
    const void* b1    = d_in[2];
    const void* W2    = d_in[3];
    const void* b2    = d_in[4];
    const void* W3    = d_in[5];
    const void* b3    = d_in[6];
    const int*  nodes = (const int*)d_in[7];
    const int*  nidx  = (const int*)d_in[8];
    const void* nmask = d_in[9];

    int* flags = (int*)d_ws;
    unsigned short* W1p = (unsigned short*)((char*)d_ws + 1024);           // 16 KB
    unsigned short* W2p = (unsigned short*)((char*)d_ws + 1024 + 16384);   // 8 KB

    prep_kernel<<<1, 1024, 0, stream>>>((const unsigned int*)table,
                                        (const unsigned int*)nmask,
                                        W1, W2, flags, W1p, W2p);
    agg_kernel<<<NN / 4, 256, 0, stream>>>(table, b1, b2, W3, b3,
                                           nodes, nidx, nmask, flags,
                                           W1p, W2p, d_out);
}

// Round 5
// 410.942 us; speedup vs baseline: 2.4114x; 1.0074x over previous
//
#include <hip/hip_runtime.h>
#include <hip/hip_bf16.h>

#define NN 16384   // N_NODES
#define KK 50      // K neighbors
#define DD 64      // EMBED_DIM

typedef __attribute__((ext_vector_type(8))) short bf16x8;   // 8 bf16 (4 VGPRs)
typedef __attribute__((ext_vector_type(4))) float f32x4;    // MFMA C/D

// ---------- bf16 helpers ----------
__device__ __forceinline__ float bf2f(unsigned short u) {
    union { unsigned int i; float f; } v;
    v.i = ((unsigned int)u) << 16;
    return v.f;
}
__device__ __forceinline__ unsigned short f2bf(float f) {
    union { float f; unsigned int i; } v; v.f = f;
    unsigned int lsb = (v.i >> 16) & 1u;
    v.i += 0x7fffu + lsb;                 // RTNE
    return (unsigned short)(v.i >> 16);
}

template<int BF16>
__device__ __forceinline__ float ldv(const void* p, size_t i) {
    if (BF16) return bf2f(((const unsigned short*)p)[i]);
    else      return ((const float*)p)[i];
}

template<int BF16>
__device__ __forceinline__ bf16x8 load8(const void* p, size_t off) {
    if (BF16) {
        return *(const bf16x8*)((const unsigned short*)p + off);   // 16B
    } else {
        const float* f = (const float*)p + off;
        bf16x8 r;
#pragma unroll
        for (int j = 0; j < 8; ++j) ((unsigned short*)&r)[j] = f2bf(f[j]);
        return r;
    }
}

// ---------- probe + weight repack (one block, 1024 threads) ----------
// flags[0]: neigh_mask uint8(1)/int32(0); flags[1]: tensors bf16(1)/f32(0)
// B fragment (16x16x32): lane holds B[k = kt*32 + (lane>>4)*8 + j][n = nt*16 + (lane&15)]
// packed [frag][lane][j]. W1 split: top (k<64, E half) and bot (k>=64, U half).
__global__ void prep_kernel(const unsigned int* __restrict__ tw,
                            const unsigned int* __restrict__ mw,
                            const void* __restrict__ W1_,
                            const void* __restrict__ W2_,
                            int* __restrict__ flags,
                            unsigned short* __restrict__ W1top,
                            unsigned short* __restrict__ W1bot,
                            unsigned short* __restrict__ W2p) {
    __shared__ int sflags[2];
    const int t = threadIdx.x;            // 1024
    if (t < 64) {
        const unsigned int w  = tw[t];
        const unsigned int lo = w & 0xFFFFu;
        const unsigned int ex = (lo >> 7) & 0xFFu;
        const bool bf_like = (ex >= 96u && ex <= 126u);
        const unsigned long long bb = __ballot(bf_like);
        bool found = false;
#pragma unroll
        for (int i = 0; i < 8; ++i) found |= (mw[t + i * 64] > 1u);
        const unsigned long long mb = __ballot(found);
        if (t == 0) {
            sflags[0] = (mb != 0ull) ? 1 : 0;
            sflags[1] = (__popcll(bb) >= 48) ? 1 : 0;
            flags[0] = sflags[0];
            flags[1] = sflags[1];
        }
    }
    __syncthreads();
    const int bf = sflags[1];
    {   // W1 [128x64]: 16 fragments; kt<2 -> top, kt>=2 -> bot
        const int f = t >> 6, lane = t & 63;
        const int kt = f >> 2, nt = f & 3;
        const int q = lane >> 4, col = lane & 15;
#pragma unroll
        for (int j = 0; j < 8; ++j) {
            const int k = kt * 32 + q * 8 + j;
            const int n = nt * 16 + col;
            const float v = bf ? bf2f(((const unsigned short*)W1_)[k * 64 + n])
                               : ((const float*)W1_)[k * 64 + n];
            unsigned short* dst = (kt < 2) ? W1top : W1bot;
            const int fl = ((kt & 1) * 4 + nt);
            dst[((size_t)fl * 64 + lane) * 8 + j] = f2bf(v);
        }
    }
    if (t < 512) {   // W2 [64x64]: 8 fragments
        const int f = t >> 6, lane = t & 63;
        const int kt = f >> 2, nt = f & 3;
        const int q = lane >> 4, col = lane & 15;
#pragma unroll
        for (int j = 0; j < 8; ++j) {
            const int k = kt * 32 + q * 8 + j;
            const int n = nt * 16 + col;
            const float v = bf ? bf2f(((const unsigned short*)W2_)[k * 64 + n])
                               : ((const float*)W2_)[k * 64 + n];
            W2p[((size_t)f * 64 + lane) * 8 + j] = f2bf(v);
        }
    }
}

// ---------- UW precompute: UW[n][c] = b1[c] + table[nodes[n]] @ W1_bot ----------
// 64 nodes per wave, 4 waves/block, 64 blocks. Output f32 [NN x 64].
template<int BF16>
__device__ __forceinline__ void uw_impl(
    const void* __restrict__ table_, const void* __restrict__ b1_,
    const int* __restrict__ nodes,
    const unsigned short* __restrict__ W1bot,
    float* __restrict__ UW)
{
    const int wave = threadIdx.x >> 6;
    const int lane = threadIdx.x & 63;
    const int q    = lane >> 4;
    const int col  = lane & 15;
    const int base = (blockIdx.x * 4 + wave) * 64;

    bf16x8 afrag[4][2];
#pragma unroll
    for (int mt = 0; mt < 4; ++mt) {
        const size_t row = (size_t)nodes[base + mt * 16 + col];
#pragma unroll
        for (int kt = 0; kt < 2; ++kt)
            afrag[mt][kt] = load8<BF16>(table_, row * 64 + kt * 32 + q * 8);
    }

    f32x4 acc[4][4];
#pragma unroll
    for (int mt = 0; mt < 4; ++mt)
#pragma unroll
        for (int nt = 0; nt < 4; ++nt) acc[mt][nt] = (f32x4){0.f, 0.f, 0.f, 0.f};

#pragma unroll
    for (int kt = 0; kt < 2; ++kt)
#pragma unroll
        for (int nt = 0; nt < 4; ++nt) {
            const bf16x8 b = *(const bf16x8*)(W1bot + ((size_t)(kt * 4 + nt) * 64 + lane) * 8);
#pragma unroll
            for (int mt = 0; mt < 4; ++mt)
                acc[mt][nt] = __builtin_amdgcn_mfma_f32_16x16x32_bf16(afrag[mt][kt], b, acc[mt][nt], 0, 0, 0);
        }

    float b1v[4];
#pragma unroll
    for (int nt = 0; nt < 4; ++nt) b1v[nt] = ldv<BF16>(b1_, nt * 16 + col);
#pragma unroll
    for (int mt = 0; mt < 4; ++mt)
#pragma unroll
        for (int nt = 0; nt < 4; ++nt)
#pragma unroll
            for (int r = 0; r < 4; ++r)
                UW[(size_t)(base + mt * 16 + q * 4 + r) * 64 + nt * 16 + col] =
                    acc[mt][nt][r] + b1v[nt];
}

__global__ __launch_bounds__(256) void uw_kernel(
    const void* __restrict__ table_, const void* __restrict__ b1_,
    const int* __restrict__ nodes, const int* __restrict__ flags,
    const unsigned short* __restrict__ W1bot, float* __restrict__ UW)
{
    if (flags[1]) uw_impl<1>(table_, b1_, nodes, W1bot, UW);
    else          uw_impl<0>(table_, b1_, nodes, W1bot, UW);
}

// ---------- main: one wave per node, 2 waves/block (19KB LDS) ----------
template<int BF16>
__device__ __forceinline__ void agg_impl(
    const void* __restrict__ table_,
    const void* __restrict__ b2_, const void* __restrict__ W3_,
    const int*  __restrict__ nodes,
    const int*  __restrict__ neigh_idx,
    const void* __restrict__ neigh_mask,
    int mu8,
    const unsigned short* __restrict__ W1top,
    const unsigned short* __restrict__ W2p,
    const float* __restrict__ UW,
    unsigned short* __restrict__ h1,     // per-wave [64][72] bf16
    float* __restrict__ scr,             // per-wave [64] f32
    void* __restrict__ out_)
{
    const int wave = threadIdx.x >> 6;
    const int lane = threadIdx.x & 63;
    const int n    = blockIdx.x * 2 + wave;
    const int q    = lane >> 4;
    const int col  = lane & 15;

    // --- row indices + mask: A-layout row m = mt*16 + col ---
    int  rowidx [4];
    bool rowmask[4];
#pragma unroll
    for (int mt = 0; mt < 4; ++mt) {
        const int k = mt * 16 + col;
        bool mk = false; int idx = 0;
        if (k < KK) {
            mk = mu8 ? (((const unsigned char*)neigh_mask)[(size_t)n * KK + k] != 0)
                     : (((const int*)neigh_mask)[(size_t)n * KK + k] != 0);
            if (mk) idx = neigh_idx[(size_t)n * KK + k];
        }
        rowidx[mt] = idx; rowmask[mt] = mk;
    }

    // --- gather E rows (kept live for the final weighted sum) ---
    bf16x8 afrag[4][2];
#pragma unroll
    for (int mt = 0; mt < 4; ++mt)
#pragma unroll
        for (int kt = 0; kt < 2; ++kt)
            afrag[mt][kt] = load8<BF16>(table_, (size_t)rowidx[mt] * 64 + kt * 32 + q * 8);

    // --- per-node center contribution (row-constant): UW[n][*] ---
    float uwv[4];
#pragma unroll
    for (int nt = 0; nt < 4; ++nt) uwv[nt] = UW[(size_t)n * 64 + nt * 16 + col];

    // --- layer 1: acc1 = E @ W1_top  (32 MFMAs) ---
    f32x4 acc1[4][4];
#pragma unroll
    for (int mt = 0; mt < 4; ++mt)
#pragma unroll
        for (int nt = 0; nt < 4; ++nt) acc1[mt][nt] = (f32x4){0.f, 0.f, 0.f, 0.f};

#pragma unroll
    for (int kt = 0; kt < 2; ++kt)
#pragma unroll
        for (int nt = 0; nt < 4; ++nt) {
            const bf16x8 b = *(const bf16x8*)(W1top + ((size_t)(kt * 4 + nt) * 64 + lane) * 8);
#pragma unroll
            for (int mt = 0; mt < 4; ++mt)
                acc1[mt][nt] = __builtin_amdgcn_mfma_f32_16x16x32_bf16(afrag[mt][kt], b, acc1[mt][nt], 0, 0, 0);
        }

    // --- h1 = relu(acc1 + UW), C layout -> LDS (A-layout-readable) ---
#pragma unroll
    for (int mt = 0; mt < 4; ++mt)
#pragma unroll
        for (int nt = 0; nt < 4; ++nt)
#pragma unroll
            for (int r = 0; r < 4; ++r) {
                const float v = fmaxf(acc1[mt][nt][r] + uwv[nt], 0.f);
                h1[(mt * 16 + q * 4 + r) * 72 + nt * 16 + col] = f2bf(v);
            }
    __builtin_amdgcn_wave_barrier();

    // --- layer 2: acc2 = H1 @ W2  (32 MFMAs) ---
    f32x4 acc2[4][4];
#pragma unroll
    for (int mt = 0; mt < 4; ++mt)
#pragma unroll
        for (int nt = 0; nt < 4; ++nt) acc2[mt][nt] = (f32x4){0.f, 0.f, 0.f, 0.f};

#pragma unroll
    for (int kt = 0; kt < 2; ++kt) {
        bf16x8 a2[4];
#pragma unroll
        for (int mt = 0; mt < 4; ++mt)
            a2[mt] = *(const bf16x8*)&h1[(mt * 16 + col) * 72 + kt * 32 + q * 8];
#pragma unroll
        for (int nt = 0; nt < 4; ++nt) {
            const bf16x8 b = *(const bf16x8*)(W2p + ((size_t)(kt * 4 + nt) * 64 + lane) * 8);
#pragma unroll
            for (int mt = 0; mt < 4; ++mt)
                acc2[mt][nt] = __builtin_amdgcn_mfma_f32_16x16x32_bf16(a2[mt], b, acc2[mt][nt], 0, 0, 0);
        }
    }

    // --- scores: s[row] = sum_n relu(acc2 + b2)[row][n] * W3[n]
    //     (b3 dropped: uniform shift, softmax-invariant) ---
    float b2v[4], w3v[4];
#pragma unroll
    for (int nt = 0; nt < 4; ++nt) {
        b2v[nt] = ldv<BF16>(b2_, nt * 16 + col);
        w3v[nt] = ldv<BF16>(W3_, nt * 16 + col);
    }

    float s[4][4];   // [mt][r]: row = mt*16 + q*4 + r
#pragma unroll
    for (int mt = 0; mt < 4; ++mt) {
        const unsigned long long bm = __ballot(rowmask[mt]);
#pragma unroll
        for (int r = 0; r < 4; ++r) {
            float p = 0.f;
#pragma unroll
            for (int nt = 0; nt < 4; ++nt)
                p += fmaxf(acc2[mt][nt][r] + b2v[nt], 0.f) * w3v[nt];
            p += __shfl_xor(p, 1, 64);
            p += __shfl_xor(p, 2, 64);
            p += __shfl_xor(p, 4, 64);
            p += __shfl_xor(p, 8, 64);
            const bool mk = (bm >> (q * 4 + r)) & 1ull;
            s[mt][r] = mk ? p : -1.0e30f;
        }
    }

    // --- masked softmax over 64 rows ---
    float mx = -3.0e38f;
#pragma unroll
    for (int mt = 0; mt < 4; ++mt)
#pragma unroll
        for (int r = 0; r < 4; ++r) mx = fmaxf(mx, s[mt][r]);
    mx = fmaxf(mx, __shfl_xor(mx, 16, 64));
    mx = fmaxf(mx, __shfl_xor(mx, 32, 64));

    float e[4][4], lsum = 0.f;
#pragma unroll
    for (int mt = 0; mt < 4; ++mt)
#pragma unroll
        for (int r = 0; r < 4; ++r) {
            e[mt][r] = expf(s[mt][r] - mx);
            lsum += e[mt][r];
        }
    lsum += __shfl_xor(lsum, 16, 64);
    lsum += __shfl_xor(lsum, 32, 64);
    const float inv = 1.f / lsum;

    // --- broadcast att[row] to row-owner lanes via 256B LDS scratch ---
    if (col == 0)
#pragma unroll
        for (int mt = 0; mt < 4; ++mt)
#pragma unroll
            for (int r = 0; r < 4; ++r)
                scr[mt * 16 + q * 4 + r] = e[mt][r] * inv;
    __builtin_amdgcn_wave_barrier();

    float attr[4];
#pragma unroll
    for (int mt = 0; mt < 4; ++mt) attr[mt] = scr[mt * 16 + col];

    // --- out[d] = sum_k att[k]*E[k][d] from the live A-fragments ---
    float v[2][8];
#pragma unroll
    for (int kt = 0; kt < 2; ++kt)
#pragma unroll
        for (int j = 0; j < 8; ++j) v[kt][j] = 0.f;
#pragma unroll
    for (int mt = 0; mt < 4; ++mt)
#pragma unroll
        for (int kt = 0; kt < 2; ++kt)
#pragma unroll
            for (int j = 0; j < 8; ++j)
                v[kt][j] += attr[mt] * bf2f(((const unsigned short*)&afrag[mt][kt])[j]);

#pragma unroll
    for (int off = 1; off <= 8; off <<= 1)
#pragma unroll
        for (int kt = 0; kt < 2; ++kt)
#pragma unroll
            for (int j = 0; j < 8; ++j)
                v[kt][j] += __shfl_xor(v[kt][j], off, 64);

    __builtin_amdgcn_wave_barrier();
    if (col == 0)
#pragma unroll
        for (int kt = 0; kt < 2; ++kt)
#pragma unroll
            for (int j = 0; j < 8; ++j)
                scr[kt * 32 + q * 8 + j] = v[kt][j];
    __builtin_amdgcn_wave_barrier();

    const float res = scr[lane];
    if (BF16) ((unsigned short*)out_)[(size_t)n * 64 + lane] = f2bf(res);
    else      ((float*)out_)[(size_t)n * 64 + lane] = res;
}

__global__ __launch_bounds__(128) void agg_kernel(
    const void* __restrict__ table_,
    const void* __restrict__ b2_, const void* __restrict__ W3_,
    const int*  __restrict__ nodes,
    const int*  __restrict__ neigh_idx,
    const void* __restrict__ neigh_mask,
    const int*  __restrict__ flags,
    const unsigned short* __restrict__ W1top,
    const unsigned short* __restrict__ W2p,
    const float* __restrict__ UW,
    void* __restrict__ out_)
{
    __shared__ unsigned short h1_sh[2][64][72];
    __shared__ float scr_sh[2][64];
    const int wave = threadIdx.x >> 6;
    if (flags[1])
        agg_impl<1>(table_, b2_, W3_, nodes, neigh_idx, neigh_mask, flags[0],
                    W1top, W2p, UW, &h1_sh[wave][0][0], &scr_sh[wave][0], out_);
    else
        agg_impl<0>(table_, b2_, W3_, nodes, neigh_idx, neigh_mask, flags[0],
                    W1top, W2p, UW, &h1_sh[wave][0][0], &scr_sh[wave][0], out_);
}

extern "C" void kernel_launch(void* const* d_in, const int* in_sizes, int n_in,
                              void* d_out, int out_size, void* d_ws, size_t ws_size,
                              hipStream_t stream) {
    const void* table = d_in[0];
    const void* W1    = d_in[1];
    const void* b1    = d_in[2];
    const void* W2    = d_in[3];
    const void* b2    = d_in[4];
    const void* W3    = d_in[5];
    const void* b3    = d_in[6]; (void)b3;   // softmax-invariant, dropped
    const int*  nodes = (const int*)d_in[7];
    const int*  nidx  = (const int*)d_in[8];
    const void* nmask = d_in[9];

    char* ws = (char*)d_ws;
    int* flags            = (int*)ws;                       // 8 B
    unsigned short* W1top = (unsigned short*)(ws + 1024);   // 8 KB
    unsigned short* W1bot = (unsigned short*)(ws + 1024 + 8192);    // 8 KB
    unsigned short* W2p   = (unsigned short*)(ws + 1024 + 16384);   // 8 KB
    float* UW             = (float*)(ws + 32768);           // 4 MB f32 [NN x 64]

    prep_kernel<<<1, 1024, 0, stream>>>((const unsigned int*)table,
                                        (const unsigned int*)nmask,
                                        W1, W2, flags, W1top, W1bot, W2p);
    uw_kernel<<<NN / 256, 256, 0, stream>>>(table, b1, nodes, flags, W1bot, UW);
    agg_kernel<<<NN / 2, 128, 0, stream>>>(table, b2, W3, nodes, nidx, nmask,
                                           flags, W1top, W2p, UW, d_out);
}